// Round 1
// baseline (79.571 us; speedup 1.0000x reference)
//
#include <hip/hip_runtime.h>

#define DIM 4096
#define NB 128

// ---------------------------------------------------------------------------
// Kernel A: apply U2 (axis i2) then U1 (axis i1) within each 256-element chunk.
// grid: NB*16 blocks x 256 threads; block = (batch b, chunk i0 = c).
// Thread t -> (i1 = t>>4, i2 = t&15).
// ---------------------------------------------------------------------------
__global__ __launch_bounds__(256)
void ulayer_a(const float* __restrict__ thetas,
              const float* __restrict__ evecs,
              const float* __restrict__ evals,
              const float* __restrict__ sre,
              const float* __restrict__ sim,
              float2* __restrict__ ws)
{
    __shared__ float  sV[256];
    __shared__ float  sC[32], sS[32];
    __shared__ float2 sG1[16][17];   // U1[i1][j]        (padded: 4 i1-groups -> distinct banks)
    __shared__ float2 sG2[16][17];   // sG2[j][i2] = U2[i2][j] (transposed for broadcast)
    __shared__ float2 x0[16][17];    // input chunk [i1][i2]
    __shared__ float2 x1[16][17];    // after U2

    const int t  = threadIdx.x;
    const int b  = blockIdx.x >> 4;
    const int c  = blockIdx.x & 15;
    const int i1 = t >> 4;
    const int i2 = t & 15;

    // stage V and per-(gate,eig) trig for gates 1,2
    sV[t] = evecs[t];
    if (t < 32) {
        const int g = (t >> 4) + 1;      // gates 1 and 2
        const int k = t & 15;
        float sn, cs;
        sincosf(thetas[g] * evals[k], &sn, &cs);
        sC[t] = cs;
        sS[t] = sn;
    }

    // load this chunk's 256 complex elements (coalesced), store interleaved
    const int d = b * DIM + c * 256 + t;
    const float xr = sre[d];
    const float xi = sim[d];
    x0[i1][i2] = make_float2(xr, xi);

    __syncthreads();

    // build gates 1 and 2: 512 entries, 2 per thread
    // U[i,j] = sum_k V[i,k] V[j,k] * (cos - i sin)
#pragma unroll
    for (int rep = 0; rep < 2; ++rep) {
        const int e  = t + (rep << 8);
        const int gg = e >> 8;           // 0 -> gate1, 1 -> gate2
        const int i  = (e >> 4) & 15;
        const int j  = e & 15;
        float gr = 0.f, gi = 0.f;
#pragma unroll
        for (int k = 0; k < 16; ++k) {
            const float vv = sV[i * 16 + k] * sV[j * 16 + k];
            gr = fmaf(vv,  sC[(gg << 4) + k], gr);
            gi = fmaf(vv, -sS[(gg << 4) + k], gi);
        }
        if (gg == 0) sG1[i][j] = make_float2(gr, gi);
        else         sG2[j][i] = make_float2(gr, gi);   // transposed store
    }
    __syncthreads();

    // pass U2: y[i1][i2] = sum_j U2[i2][j] * x0[i1][j]
    {
        float ar = 0.f, ai = 0.f;
#pragma unroll
        for (int j = 0; j < 16; ++j) {
            const float2 g = sG2[j][i2];   // 16 consecutive float2 -> conflict-free + broadcast
            const float2 x = x0[i1][j];    // wave-uniform per i1-group -> broadcast
            ar = fmaf(g.x,  x.x, ar);
            ar = fmaf(-g.y, x.y, ar);
            ai = fmaf(g.x,  x.y, ai);
            ai = fmaf(g.y,  x.x, ai);
        }
        x1[i1][i2] = make_float2(ar, ai);
    }
    __syncthreads();

    // pass U1: y[i1][i2] = sum_j U1[i1][j] * x1[j][i2], write straight to ws
    {
        float ar = 0.f, ai = 0.f;
#pragma unroll
        for (int j = 0; j < 16; ++j) {
            const float2 g = sG1[i1][j];   // broadcast within i1-group
            const float2 x = x1[j][i2];    // 16 consecutive float2 -> conflict-free
            ar = fmaf(g.x,  x.x, ar);
            ar = fmaf(-g.y, x.y, ar);
            ai = fmaf(g.x,  x.y, ai);
            ai = fmaf(g.y,  x.x, ai);
        }
        ws[d] = make_float2(ar, ai);       // coalesced 8B stores
    }
}

// ---------------------------------------------------------------------------
// Kernel B: apply U0 (axis i0, stride 256) per fiber; fibers in registers.
// grid: NB*4 blocks x 256 threads; block = (batch b, fiber-part fp).
// Thread t -> (q = t>>6 : output quarter i0 = 4q..4q+3, fl = t&63 : fiber).
// q is wave-uniform -> gate reads are LDS broadcasts.
// ---------------------------------------------------------------------------
__global__ __launch_bounds__(256)
void ulayer_b(const float* __restrict__ thetas,
              const float* __restrict__ evecs,
              const float* __restrict__ evals,
              const float2* __restrict__ ws,
              float* __restrict__ out)
{
    __shared__ float  sV[256];
    __shared__ float  sC[16], sS[16];
    __shared__ float2 sG0[16][16];

    const int t  = threadIdx.x;
    const int b  = blockIdx.x >> 2;
    const int fp = blockIdx.x & 3;
    const int q  = t >> 6;
    const int fl = t & 63;
    const int f  = fp * 64 + fl;     // fiber index (i1*16 + i2), 0..255

    // issue the 16 fiber loads immediately; latency hides under gate build
    float2 x[16];
    const float2* __restrict__ wsb = ws + (size_t)b * DIM;
#pragma unroll
    for (int j = 0; j < 16; ++j) x[j] = wsb[j * 256 + f];   // coalesced per j

    sV[t] = evecs[t];
    if (t < 16) {
        float sn, cs;
        sincosf(thetas[0] * evals[t], &sn, &cs);
        sC[t] = cs;
        sS[t] = sn;
    }
    __syncthreads();

    // build gate 0: 256 entries, 1 per thread
    {
        const int i = t >> 4, j = t & 15;
        float gr = 0.f, gi = 0.f;
#pragma unroll
        for (int k = 0; k < 16; ++k) {
            const float vv = sV[i * 16 + k] * sV[j * 16 + k];
            gr = fmaf(vv,  sC[k], gr);
            gi = fmaf(vv, -sS[k], gi);
        }
        sG0[i][j] = make_float2(gr, gi);
    }
    __syncthreads();

    float* __restrict__ ore = out + (size_t)b * DIM;
    float* __restrict__ oim = out + (size_t)NB * DIM + (size_t)b * DIM;

#pragma unroll
    for (int r = 0; r < 4; ++r) {
        const int i0 = q * 4 + r;
        float ar = 0.f, ai = 0.f;
#pragma unroll
        for (int j = 0; j < 16; ++j) {
            const float2 g = sG0[i0][j];   // wave-uniform -> broadcast
            ar = fmaf(g.x,  x[j].x, ar);
            ar = fmaf(-g.y, x[j].y, ar);
            ai = fmaf(g.x,  x[j].y, ai);
            ai = fmaf(g.y,  x[j].x, ai);
        }
        const int od = i0 * 256 + f;       // coalesced 4B stores per i0
        ore[od] = ar;
        oim[od] = ai;
    }
}

extern "C" void kernel_launch(void* const* d_in, const int* in_sizes, int n_in,
                              void* d_out, int out_size, void* d_ws, size_t ws_size,
                              hipStream_t stream) {
    const float* thetas = (const float*)d_in[0];
    const float* evecs  = (const float*)d_in[1];
    const float* evals  = (const float*)d_in[2];
    const float* sre    = (const float*)d_in[3];
    const float* sim    = (const float*)d_in[4];
    float* outp = (float*)d_out;
    float2* ws  = (float2*)d_ws;   // 128*4096 float2 = 4 MiB intermediate

    ulayer_a<<<NB * 16, 256, 0, stream>>>(thetas, evecs, evals, sre, sim, ws);
    ulayer_b<<<NB * 4,  256, 0, stream>>>(thetas, evecs, evals, ws, outp);
}

// Round 2
// 73.126 us; speedup vs baseline: 1.0881x; 1.0881x over previous
//
#include <hip/hip_runtime.h>

#define DIM 4096
#define NB 128
#define P 17   // padded inner stride (float2 units) for LDS fiber buffers

// One fused dispatch. Block = (batch b, i1-quarter qq). 256 threads.
// Pass order: U1 (from global, coupled axis read per-thread), U2, U0.
// Each block computes only its 1024 outputs (i1 = qq*4 .. qq*4+3).
__global__ __launch_bounds__(256)
void ulayer_fused(const float* __restrict__ thetas,
                  const float* __restrict__ evecs,
                  const float* __restrict__ evals,
                  const float* __restrict__ sre,
                  const float* __restrict__ sim,
                  float* __restrict__ out)
{
    __shared__ float  sV[256];
    __shared__ float  sC[48], sS[48];
    __shared__ float2 sG[3][16][16];   // all three gates
    __shared__ float2 A[16][4][P];     // y1: [i0][i1loc][i2]
    __shared__ float2 B[4][16][P];     // y2: [i1loc][i2][i0]

    const int t  = threadIdx.x;
    const int b  = blockIdx.x >> 2;
    const int qq = blockIdx.x & 3;

    // ---- issue global loads immediately; latency hides under gate build ----
    // thread (i0 = t>>4, i2 = t&15) reads the full i1-fiber (16 x stride 64B)
    const int i0 = t >> 4;
    const int i2 = t & 15;
    const float* __restrict__ pr = sre + (size_t)b * DIM + i0 * 256 + i2;
    const float* __restrict__ pi = sim + (size_t)b * DIM + i0 * 256 + i2;
    float xr[16], xi[16];
#pragma unroll
    for (int j = 0; j < 16; ++j) { xr[j] = pr[j * 16]; xi[j] = pi[j * 16]; }

    // ---- stage V and per-(gate,eig) trig ----
    sV[t] = evecs[t];
    if (t < 48) {
        const int g = t >> 4, k = t & 15;
        float sn, cs;
        sincosf(thetas[g] * evals[k], &sn, &cs);
        sC[t] = cs;
        sS[t] = sn;
    }
    __syncthreads();

    // ---- build the three 16x16 gates: U[i,j] = sum_k V[i,k]V[j,k](cos - i sin) ----
#pragma unroll
    for (int rep = 0; rep < 3; ++rep) {
        const int e = t + (rep << 8);
        const int g = e >> 8;
        const int i = (e >> 4) & 15;
        const int j = e & 15;
        float gr = 0.f, gi = 0.f;
#pragma unroll
        for (int k = 0; k < 16; ++k) {
            const float vv = sV[i * 16 + k] * sV[j * 16 + k];
            gr = fmaf(vv,  sC[(g << 4) + k], gr);
            gi = fmaf(vv, -sS[(g << 4) + k], gi);
        }
        sG[g][i][j] = make_float2(gr, gi);
    }
    __syncthreads();

    // ---- pass U1 (axis i1): outputs only for i1 = qq*4 + l ----
    // gate reads fully uniform -> LDS broadcast; A-writes bank-uniform (pad 17)
#pragma unroll
    for (int l = 0; l < 4; ++l) {
        float ar = 0.f, ai = 0.f;
#pragma unroll
        for (int j = 0; j < 16; ++j) {
            const float2 g = sG[1][qq * 4 + l][j];
            ar = fmaf(g.x,  xr[j], ar);
            ar = fmaf(-g.y, xi[j], ar);
            ai = fmaf(g.x,  xi[j], ai);
            ai = fmaf(g.y,  xr[j], ai);
        }
        A[i0][l][i2] = make_float2(ar, ai);
    }
    __syncthreads();

    // ---- pass U2 (axis i2) ----
    // ig = t>>6 is wave-uniform -> gate rows broadcast; fiber reads bank-uniform
    {
        const int ig  = t >> 6;        // output i2 group: rows ig*4 .. ig*4+3
        const int fid = t & 63;        // fiber (i0 = fid>>2, l = fid&3)
        const int fi0 = fid >> 2;
        const int fl  = fid & 3;
        float2 x2[16];
#pragma unroll
        for (int j = 0; j < 16; ++j) x2[j] = A[fi0][fl][j];
#pragma unroll
        for (int q = 0; q < 4; ++q) {
            const int r = ig * 4 + q;  // output i2
            float ar = 0.f, ai = 0.f;
#pragma unroll
            for (int j = 0; j < 16; ++j) {
                const float2 g = sG[2][r][j];
                ar = fmaf(g.x,  x2[j].x, ar);
                ar = fmaf(-g.y, x2[j].y, ar);
                ai = fmaf(g.x,  x2[j].y, ai);
                ai = fmaf(g.y,  x2[j].x, ai);
            }
            B[fl][r][fi0] = make_float2(ar, ai);
        }
    }
    __syncthreads();

    // ---- pass U0 (axis i0) + coalesced store ----
    // rg = t>>6 wave-uniform -> gate broadcast; stores 64 consecutive floats/instr
    {
        const int rg = t >> 6;         // output i0 group: rows rg*4 .. rg*4+3
        const int fl = t & 63;         // fiber (l = fl>>4, i2f = fl&15)
        const int l   = fl >> 4;
        const int i2f = fl & 15;
        float2 x0[16];
#pragma unroll
        for (int j = 0; j < 16; ++j) x0[j] = B[l][i2f][j];

        float* __restrict__ ore = out + (size_t)b * DIM;
        float* __restrict__ oim = out + (size_t)NB * DIM + (size_t)b * DIM;
#pragma unroll
        for (int r = 0; r < 4; ++r) {
            const int ro = rg * 4 + r; // output i0
            float ar = 0.f, ai = 0.f;
#pragma unroll
            for (int j = 0; j < 16; ++j) {
                const float2 g = sG[0][ro][j];
                ar = fmaf(g.x,  x0[j].x, ar);
                ar = fmaf(-g.y, x0[j].y, ar);
                ai = fmaf(g.x,  x0[j].y, ai);
                ai = fmaf(g.y,  x0[j].x, ai);
            }
            const int od = ro * 256 + (qq * 4 + l) * 16 + i2f;
            ore[od] = ar;
            oim[od] = ai;
        }
    }
}

extern "C" void kernel_launch(void* const* d_in, const int* in_sizes, int n_in,
                              void* d_out, int out_size, void* d_ws, size_t ws_size,
                              hipStream_t stream) {
    const float* thetas = (const float*)d_in[0];
    const float* evecs  = (const float*)d_in[1];
    const float* evals  = (const float*)d_in[2];
    const float* sre    = (const float*)d_in[3];
    const float* sim    = (const float*)d_in[4];
    float* outp = (float*)d_out;
    ulayer_fused<<<NB * 4, 256, 0, stream>>>(thetas, evecs, evals, sre, sim, outp);
}